// Round 1
// baseline (337.480 us; speedup 1.0000x reference)
//
#include <hip/hip_runtime.h>
#include <hip/hip_bf16.h>

#define BATCH 2
#define SEQ 2048
#define DMODEL 1024
#define NHEAD 16
#define DHEAD 64
#define NQKV 3072
#define DINNER 1024

typedef __attribute__((ext_vector_type(4))) short short4v;
typedef __attribute__((ext_vector_type(8))) short short8v;
typedef __attribute__((ext_vector_type(4))) float f32x4;

__device__ __forceinline__ unsigned short f2bf(float f) {
  union { float f; unsigned int u; } c; c.f = f;
  unsigned int u = c.u;
  u += 0x7fffu + ((u >> 16) & 1u);
  return (unsigned short)(u >> 16);
}

__device__ __forceinline__ short8v load_frag(const unsigned short* p0, const unsigned short* p1) {
  union { short8v v8; short4v v4[2]; } u;
  u.v4[0] = *(const short4v*)p0;
  u.v4[1] = *(const short4v*)p1;
  return u.v8;
}

// ---------------- transpose + cast fp32 [K][N] -> bf16 [N][K] ----------------
__global__ __launch_bounds__(256) void transpose_cast_kernel(const float* __restrict__ in,
                                                             unsigned short* __restrict__ out,
                                                             int K, int N) {
  __shared__ float tile[32][33];
  const int tiles_n = N >> 5;
  const int tn = blockIdx.x % tiles_n;
  const int tk = blockIdx.x / tiles_n;
  const int k0 = tk << 5, n0 = tn << 5;
  const int t = threadIdx.x;
#pragma unroll
  for (int p = 0; p < 4; p++) {
    const int e = p * 256 + t;
    const int r = e >> 5, c = e & 31;
    tile[r][c] = in[(size_t)(k0 + r) * N + n0 + c];
  }
  __syncthreads();
#pragma unroll
  for (int p = 0; p < 4; p++) {
    const int e = p * 256 + t;
    const int r = e >> 5, c = e & 31;
    out[(size_t)(n0 + r) * K + k0 + c] = f2bf(tile[c][r]);
  }
}

// ---------------- RMSNorm (F.normalize * sqrt(dim) * gamma) -> bf16 ----------
__global__ __launch_bounds__(256) void rmsnorm_kernel(const float* __restrict__ x,
                                                      const float* __restrict__ gamma,
                                                      unsigned short* __restrict__ out) {
  const int row = blockIdx.x;  // 0..4095
  const int t = threadIdx.x;   // 256, 4 floats each
  const float* xr = x + (size_t)row * DMODEL;
  float4 v = ((const float4*)xr)[t];
  float ss = v.x * v.x + v.y * v.y + v.z * v.z + v.w * v.w;
#pragma unroll
  for (int off = 1; off < 64; off <<= 1) ss += __shfl_xor(ss, off);
  __shared__ float wss[4];
  if ((t & 63) == 0) wss[t >> 6] = ss;
  __syncthreads();
  const float tot = wss[0] + wss[1] + wss[2] + wss[3];
  float l2 = sqrtf(tot);
  l2 = fmaxf(l2, 1e-12f);
  const float s = 32.0f / l2;  // sqrt(1024)/l2
  const float4 gm = ((const float4*)gamma)[t];
  unsigned short o[4];
  o[0] = f2bf(v.x * s * gm.x);
  o[1] = f2bf(v.y * s * gm.y);
  o[2] = f2bf(v.z * s * gm.z);
  o[3] = f2bf(v.w * s * gm.w);
  unsigned short* op = out + (size_t)row * DMODEL + t * 4;
  *(short4v*)op = *(short4v*)o;
}

// ---------------- shared GEMM core: C[128x128] = A[128xK] * Bt[128xK]^T ------
#define BM 128
#define BN 128
#define BKT 32
#define LSTR 40  // padded LDS row stride (shorts); 80B rows keep 16B alignment

__device__ void gemm_core(const unsigned short* __restrict__ A,
                          const unsigned short* __restrict__ Bt, int K, int rowBase,
                          int colBase, unsigned short* sA, unsigned short* sB,
                          f32x4 acc[4][4]) {
  const int t = threadIdx.x;
  const int lane = t & 63, wave = t >> 6;
  const int l15 = lane & 15, g = lane >> 4;
  const int wr = (wave >> 1) * 64, wc = (wave & 1) * 64;
#pragma unroll
  for (int m = 0; m < 4; m++)
#pragma unroll
    for (int n = 0; n < 4; n++) acc[m][n] = (f32x4){0.f, 0.f, 0.f, 0.f};
  const int srow = t >> 1;
  const int soff = (t & 1) * 16;
  const unsigned short* Arow = A + (size_t)(rowBase + srow) * K + soff;
  const unsigned short* Brow = Bt + (size_t)(colBase + srow) * K + soff;
  unsigned short* sArow = sA + srow * LSTR + soff;
  unsigned short* sBrow = sB + srow * LSTR + soff;
  for (int k0 = 0; k0 < K; k0 += BKT) {
    __syncthreads();
    *(short8v*)(sArow) = *(const short8v*)(Arow + k0);
    *(short8v*)(sArow + 8) = *(const short8v*)(Arow + k0 + 8);
    *(short8v*)(sBrow) = *(const short8v*)(Brow + k0);
    *(short8v*)(sBrow + 8) = *(const short8v*)(Brow + k0 + 8);
    __syncthreads();
    short8v af[4], bf[4];
#pragma unroll
    for (int m = 0; m < 4; m++) {
      const unsigned short* p = sA + (wr + m * 16 + l15) * LSTR + 4 * g;
      af[m] = load_frag(p, p + 16);
    }
#pragma unroll
    for (int n = 0; n < 4; n++) {
      const unsigned short* p = sB + (wc + n * 16 + l15) * LSTR + 4 * g;
      bf[n] = load_frag(p, p + 16);
    }
#pragma unroll
    for (int m = 0; m < 4; m++)
#pragma unroll
      for (int n = 0; n < 4; n++)
        acc[m][n] = __builtin_amdgcn_mfma_f32_16x16x32_bf16(af[m], bf[n], acc[m][n], 0, 0, 0);
  }
}

// ---------------- QKV GEMM + scatter epilogue --------------------------------
__global__ __launch_bounds__(256) void qkv_gemm_kernel(const unsigned short* __restrict__ A,
                                                       const unsigned short* __restrict__ Bt,
                                                       unsigned short* __restrict__ qb,
                                                       unsigned short* __restrict__ kb,
                                                       unsigned short* __restrict__ vb) {
  __shared__ unsigned short sA[BM * LSTR];
  __shared__ unsigned short sB[BN * LSTR];
  const int nbn = NQKV / BN;  // 24
  const int bm = blockIdx.x / nbn, bn = blockIdx.x % nbn;
  f32x4 acc[4][4];
  gemm_core(A, Bt, DMODEL, bm * BM, bn * BN, sA, sB, acc);
  const int t = threadIdx.x, lane = t & 63, wave = t >> 6;
  const int l15 = lane & 15, g = lane >> 4;
  const int wr = (wave >> 1) * 64, wc = (wave & 1) * 64;
#pragma unroll
  for (int m = 0; m < 4; m++)
#pragma unroll
    for (int n = 0; n < 4; n++) {
      const int col = bn * BN + wc + n * 16 + l15;
      const int part = col >> 10;
      const int h = (col >> 6) & 15;
      const int d = col & 63;
#pragma unroll
      for (int r = 0; r < 4; r++) {
        const int row = bm * BM + wr + m * 16 + 4 * g + r;
        const int bb = row >> 11, i = row & 2047;
        const size_t idx = (((size_t)(bb * NHEAD + h)) * SEQ + i) * DHEAD + d;
        const float v = acc[m][n][r];
        if (part == 0) qb[idx] = f2bf(v * 0.125f);  // q * d^-0.5
        else if (part == 1) kb[idx] = f2bf(v);
        else vb[idx] = f2bf(v);
      }
    }
}

// ---------------- output GEMM: d_out = attn_out @ w_out ----------------------
__global__ __launch_bounds__(256) void out_gemm_kernel(const unsigned short* __restrict__ A,
                                                       const unsigned short* __restrict__ Bt,
                                                       float* __restrict__ C) {
  __shared__ unsigned short sA[BM * LSTR];
  __shared__ unsigned short sB[BN * LSTR];
  const int nbn = DMODEL / BN;  // 8
  const int bm = blockIdx.x / nbn, bn = blockIdx.x % nbn;
  f32x4 acc[4][4];
  gemm_core(A, Bt, DINNER, bm * BM, bn * BN, sA, sB, acc);
  const int t = threadIdx.x, lane = t & 63, wave = t >> 6;
  const int l15 = lane & 15, g = lane >> 4;
  const int wr = (wave >> 1) * 64, wc = (wave & 1) * 64;
#pragma unroll
  for (int m = 0; m < 4; m++)
#pragma unroll
    for (int n = 0; n < 4; n++) {
      const int col = bn * BN + wc + n * 16 + l15;
#pragma unroll
      for (int r = 0; r < 4; r++) {
        const int row = bm * BM + wr + m * 16 + 4 * g + r;
        C[(size_t)row * DMODEL + col] = acc[m][n][r];
      }
    }
}

// ---------------- causal flash attention -------------------------------------
#define QBLK 128
#define KBLK 32
#define SQS 72  // 144B rows: 16B-aligned, spreads banks
#define SVS 40
#define SPS 40

__global__ __launch_bounds__(256) void attn_kernel(const unsigned short* __restrict__ qb,
                                                   const unsigned short* __restrict__ kb,
                                                   const unsigned short* __restrict__ vb,
                                                   unsigned short* __restrict__ ob) {
  __shared__ unsigned short sQ[QBLK * SQS];
  __shared__ unsigned short sK[KBLK * SQS];
  __shared__ unsigned short sVt[DHEAD * SVS];
  __shared__ unsigned short sP[4][32 * SPS];
  const int bh = blockIdx.x >> 4;  // b*16+h
  const int qblk = blockIdx.x & 15;
  const int q0 = qblk * QBLK;
  const unsigned short* qptr = qb + (size_t)bh * SEQ * DHEAD;
  const unsigned short* kptr = kb + (size_t)bh * SEQ * DHEAD;
  const unsigned short* vptr = vb + (size_t)bh * SEQ * DHEAD;
  const int t = threadIdx.x, lane = t & 63, wave = t >> 6;
  const int l15 = lane & 15, g = lane >> 4;

  {  // stage Q tile 128x64
    const int row = t >> 1, hb = (t & 1) * 32;
#pragma unroll
    for (int jj = 0; jj < 4; jj++)
      *(short8v*)(sQ + row * SQS + hb + jj * 8) =
          *(const short8v*)(qptr + (size_t)(q0 + row) * DHEAD + hb + jj * 8);
  }

  float rm[2][4], rl[2][4];
  f32x4 acc_o[2][4];
#pragma unroll
  for (int m = 0; m < 2; m++)
#pragma unroll
    for (int r = 0; r < 4; r++) {
      rm[m][r] = -__builtin_inff();
      rl[m][r] = 0.f;
    }
#pragma unroll
  for (int m = 0; m < 2; m++)
#pragma unroll
    for (int df = 0; df < 4; df++) acc_o[m][df] = (f32x4){0.f, 0.f, 0.f, 0.f};

  const int my_q0 = q0 + wave * 32;
  const int nk = (q0 + QBLK) / KBLK;
  const int vrow = t >> 3, vd0 = (t & 7) * 8;
  for (int kt = 0; kt < nk; kt++) {
    const int k0 = kt * KBLK;
    __syncthreads();
    // stage K tile [32][64] and V^T tile [64][32]
    *(short8v*)(sK + vrow * SQS + vd0) =
        *(const short8v*)(kptr + (size_t)(k0 + vrow) * DHEAD + vd0);
    {
      short8v vv = *(const short8v*)(vptr + (size_t)(k0 + vrow) * DHEAD + vd0);
#pragma unroll
      for (int jj = 0; jj < 8; jj++)
        sVt[(vd0 + jj) * SVS + vrow] = (unsigned short)vv[jj];
    }
    __syncthreads();
    if (k0 < my_q0 + 32) {  // wave needs this key tile
      f32x4 s[2][2];
#pragma unroll
      for (int m = 0; m < 2; m++)
#pragma unroll
        for (int n = 0; n < 2; n++) s[m][n] = (f32x4){0.f, 0.f, 0.f, 0.f};
#pragma unroll
      for (int kk = 0; kk < 2; kk++) {
        short8v aq[2], bk[2];
#pragma unroll
        for (int m = 0; m < 2; m++) {
          const unsigned short* p = sQ + (wave * 32 + m * 16 + l15) * SQS + kk * 32 + 4 * g;
          aq[m] = load_frag(p, p + 16);
        }
#pragma unroll
        for (int n = 0; n < 2; n++) {
          const unsigned short* p = sK + (n * 16 + l15) * SQS + kk * 32 + 4 * g;
          bk[n] = load_frag(p, p + 16);
        }
#pragma unroll
        for (int m = 0; m < 2; m++)
#pragma unroll
          for (int n = 0; n < 2; n++)
            s[m][n] = __builtin_amdgcn_mfma_f32_16x16x32_bf16(aq[m], bk[n], s[m][n], 0, 0, 0);
      }
      // causal mask + online softmax (rows live in 16-lane groups)
#pragma unroll
      for (int m = 0; m < 2; m++) {
#pragma unroll
        for (int r = 0; r < 4; r++) {
          const int rowg = my_q0 + m * 16 + 4 * g + r;
          float mx = -__builtin_inff();
#pragma unroll
          for (int n = 0; n < 2; n++) {
            const int keyg = k0 + n * 16 + l15;
            float v = s[m][n][r];
            v = (keyg > rowg) ? -__builtin_inff() : v;
            s[m][n][r] = v;
            mx = fmaxf(mx, v);
          }
#pragma unroll
          for (int off = 1; off < 16; off <<= 1) mx = fmaxf(mx, __shfl_xor(mx, off));
          const float nm = fmaxf(rm[m][r], mx);
          const float alpha = __expf(rm[m][r] - nm);
          rm[m][r] = nm;
          float psum = 0.f;
#pragma unroll
          for (int n = 0; n < 2; n++) {
            const float p = __expf(s[m][n][r] - nm);
            s[m][n][r] = p;
            psum += p;
          }
#pragma unroll
          for (int off = 1; off < 16; off <<= 1) psum += __shfl_xor(psum, off);
          rl[m][r] = rl[m][r] * alpha + psum;
#pragma unroll
          for (int df = 0; df < 4; df++) acc_o[m][df][r] *= alpha;
        }
      }
      // P -> LDS (per-wave buffer), re-fragment as MFMA A operand
      unsigned short* sPw = sP[wave];
#pragma unroll
      for (int m = 0; m < 2; m++)
#pragma unroll
        for (int n = 0; n < 2; n++)
#pragma unroll
          for (int r = 0; r < 4; r++)
            sPw[(m * 16 + 4 * g + r) * SPS + n * 16 + l15] = f2bf(s[m][n][r]);
      asm volatile("s_waitcnt lgkmcnt(0)" ::: "memory");
      short8v pa[2];
#pragma unroll
      for (int m = 0; m < 2; m++) {
        const unsigned short* p = sPw + (m * 16 + l15) * SPS + 4 * g;
        pa[m] = load_frag(p, p + 16);
      }
#pragma unroll
      for (int df = 0; df < 4; df++) {
        const unsigned short* p = sVt + (df * 16 + l15) * SVS + 4 * g;
        const short8v bv = load_frag(p, p + 16);
#pragma unroll
        for (int m = 0; m < 2; m++)
          acc_o[m][df] = __builtin_amdgcn_mfma_f32_16x16x32_bf16(pa[m], bv, acc_o[m][df], 0, 0, 0);
      }
    }
  }
  // epilogue: ob[b][i][h*64+d] = O / l
  const int bb = bh >> 4, hh = bh & 15;
#pragma unroll
  for (int m = 0; m < 2; m++)
#pragma unroll
    for (int r = 0; r < 4; r++) {
      const int i = my_q0 + m * 16 + 4 * g + r;
      const float inv = 1.0f / rl[m][r];
#pragma unroll
      for (int df = 0; df < 4; df++) {
        const int d = df * 16 + l15;
        ob[((size_t)bb * SEQ + i) * DINNER + hh * DHEAD + d] = f2bf(acc_o[m][df][r] * inv);
      }
    }
}

extern "C" void kernel_launch(void* const* d_in, const int* in_sizes, int n_in,
                              void* d_out, int out_size, void* d_ws, size_t ws_size,
                              hipStream_t stream) {
  (void)in_sizes; (void)n_in; (void)out_size; (void)ws_size;
  const float* x = (const float*)d_in[0];
  const float* gamma = (const float*)d_in[1];
  const float* w_qkv = (const float*)d_in[2];
  const float* w_out = (const float*)d_in[3];
  float* out = (float*)d_out;
  char* ws = (char*)d_ws;
  unsigned short* wqkvT = (unsigned short*)(ws);                // 3072*1024*2 = 6291456
  unsigned short* woutT = (unsigned short*)(ws + 6291456);      // 1024*1024*2 = 2097152
  unsigned short* normed = (unsigned short*)(ws + 8388608);     // 4096*1024*2 = 8388608
  unsigned short* qbuf = (unsigned short*)(ws + 16777216);      // 8388608
  unsigned short* kbuf = (unsigned short*)(ws + 25165824);      // 8388608
  unsigned short* vbuf = (unsigned short*)(ws + 33554432);      // 8388608
  unsigned short* aout = (unsigned short*)(ws + 41943040);      // 8388608  (total 48MB)

  hipLaunchKernelGGL(transpose_cast_kernel, dim3((DMODEL / 32) * (NQKV / 32)), dim3(256), 0,
                     stream, w_qkv, wqkvT, DMODEL, NQKV);
  hipLaunchKernelGGL(transpose_cast_kernel, dim3((DINNER / 32) * (DMODEL / 32)), dim3(256), 0,
                     stream, w_out, woutT, DINNER, DMODEL);
  hipLaunchKernelGGL(rmsnorm_kernel, dim3(BATCH * SEQ), dim3(256), 0, stream, x, gamma, normed);
  hipLaunchKernelGGL(qkv_gemm_kernel, dim3((BATCH * SEQ / BM) * (NQKV / BN)), dim3(256), 0,
                     stream, normed, wqkvT, qbuf, kbuf, vbuf);
  hipLaunchKernelGGL(attn_kernel, dim3(BATCH * NHEAD * (SEQ / QBLK)), dim3(256), 0, stream,
                     qbuf, kbuf, vbuf, aout);
  hipLaunchKernelGGL(out_gemm_kernel, dim3((BATCH * SEQ / BM) * (DMODEL / BN)), dim3(256), 0,
                     stream, aout, woutT, out);
}

// Round 2
// 325.936 us; speedup vs baseline: 1.0354x; 1.0354x over previous
//
#include <hip/hip_runtime.h>
#include <hip/hip_bf16.h>

#define BATCH 2
#define SEQ 2048
#define DMODEL 1024
#define NHEAD 16
#define DHEAD 64
#define NQKV 3072
#define DINNER 1024

typedef __attribute__((ext_vector_type(4))) short short4v;
typedef __attribute__((ext_vector_type(8))) short short8v;
typedef __attribute__((ext_vector_type(4))) float f32x4;

__device__ __forceinline__ unsigned short f2bf(float f) {
  union { float f; unsigned int u; } c; c.f = f;
  unsigned int u = c.u;
  u += 0x7fffu + ((u >> 16) & 1u);
  return (unsigned short)(u >> 16);
}

__device__ __forceinline__ short8v load_frag(const unsigned short* p0, const unsigned short* p1) {
  union { short8v v8; short4v v4[2]; } u;
  u.v4[0] = *(const short4v*)p0;
  u.v4[1] = *(const short4v*)p1;
  return u.v8;
}

#define GL16(gp, lp)                                             \
  __builtin_amdgcn_global_load_lds(                              \
      (__attribute__((address_space(1))) void*)(gp),             \
      (__attribute__((address_space(3))) void*)(lp), 16, 0, 0)

// ---------------- transpose + cast fp32 [K][N] -> bf16 [N][K] ----------------
__global__ __launch_bounds__(256) void transpose_cast_kernel(const float* __restrict__ in,
                                                             unsigned short* __restrict__ out,
                                                             int K, int N) {
  __shared__ float tile[32][33];
  const int tiles_n = N >> 5;
  const int tn = blockIdx.x % tiles_n;
  const int tk = blockIdx.x / tiles_n;
  const int k0 = tk << 5, n0 = tn << 5;
  const int t = threadIdx.x;
#pragma unroll
  for (int p = 0; p < 4; p++) {
    const int e = p * 256 + t;
    const int r = e >> 5, c = e & 31;
    tile[r][c] = in[(size_t)(k0 + r) * N + n0 + c];
  }
  __syncthreads();
#pragma unroll
  for (int p = 0; p < 4; p++) {
    const int e = p * 256 + t;
    const int r = e >> 5, c = e & 31;
    out[(size_t)(n0 + r) * K + k0 + c] = f2bf(tile[c][r]);
  }
}

// ---------------- RMSNorm (F.normalize * sqrt(dim) * gamma) -> bf16 ----------
__global__ __launch_bounds__(256) void rmsnorm_kernel(const float* __restrict__ x,
                                                      const float* __restrict__ gamma,
                                                      unsigned short* __restrict__ out) {
  const int row = blockIdx.x;
  const int t = threadIdx.x;
  const float* xr = x + (size_t)row * DMODEL;
  float4 v = ((const float4*)xr)[t];
  float ss = v.x * v.x + v.y * v.y + v.z * v.z + v.w * v.w;
#pragma unroll
  for (int off = 1; off < 64; off <<= 1) ss += __shfl_xor(ss, off);
  __shared__ float wss[4];
  if ((t & 63) == 0) wss[t >> 6] = ss;
  __syncthreads();
  const float tot = wss[0] + wss[1] + wss[2] + wss[3];
  float l2 = sqrtf(tot);
  l2 = fmaxf(l2, 1e-12f);
  const float s = 32.0f / l2;  // sqrt(1024)/l2
  const float4 gm = ((const float4*)gamma)[t];
  unsigned short o[4];
  o[0] = f2bf(v.x * s * gm.x);
  o[1] = f2bf(v.y * s * gm.y);
  o[2] = f2bf(v.z * s * gm.z);
  o[3] = f2bf(v.w * s * gm.w);
  unsigned short* op = out + (size_t)row * DMODEL + t * 4;
  *(short4v*)op = *(short4v*)o;
}

// ---------------- shared GEMM core (m97 structure): global_load_lds, linear LDS
#define BM 128
#define BN 128
#define BKT 32

__device__ void gemm_core(const unsigned short* __restrict__ A,
                          const unsigned short* __restrict__ Bt, int K, int rowBase,
                          int colBase, unsigned short* sA, unsigned short* sB,
                          f32x4 acc[4][4]) {
  const int t = threadIdx.x;
  const int lane = t & 63, wave = t >> 6;
  const int l15 = lane & 15, g = lane >> 4;
  const int wr = (wave >> 1) * 64, wc = (wave & 1) * 64;
#pragma unroll
  for (int m = 0; m < 4; m++)
#pragma unroll
    for (int n = 0; n < 4; n++) acc[m][n] = (f32x4){0.f, 0.f, 0.f, 0.f};
  // staging: tile [128][32] shorts = 8KB = 512 x 16B chunks; thread t covers
  // chunks t and t+256. chunk c: row = c>>2, col-offset = (c&3)*8 shorts.
  const int r0 = t >> 2, o0 = (t & 3) * 8;
  const unsigned short* Ag0 = A + (size_t)(rowBase + r0) * K + o0;
  const unsigned short* Ag1 = A + (size_t)(rowBase + r0 + 64) * K + o0;
  const unsigned short* Bg0 = Bt + (size_t)(colBase + r0) * K + o0;
  const unsigned short* Bg1 = Bt + (size_t)(colBase + r0 + 64) * K + o0;
  unsigned short* sA0 = sA + t * 8;
  unsigned short* sA1 = sA + (t + 256) * 8;
  unsigned short* sB0 = sB + t * 8;
  unsigned short* sB1 = sB + (t + 256) * 8;
  for (int k0 = 0; k0 < K; k0 += BKT) {
    __syncthreads();
    GL16(Ag0 + k0, sA0);
    GL16(Ag1 + k0, sA1);
    GL16(Bg0 + k0, sB0);
    GL16(Bg1 + k0, sB1);
    asm volatile("s_waitcnt vmcnt(0)" ::: "memory");
    __syncthreads();
    short8v af[4], bf[4];
#pragma unroll
    for (int m = 0; m < 4; m++) {
      const unsigned short* p = sA + (wr + m * 16 + l15) * BKT + 4 * g;
      af[m] = load_frag(p, p + 16);
    }
#pragma unroll
    for (int n = 0; n < 4; n++) {
      const unsigned short* p = sB + (wc + n * 16 + l15) * BKT + 4 * g;
      bf[n] = load_frag(p, p + 16);
    }
#pragma unroll
    for (int m = 0; m < 4; m++)
#pragma unroll
      for (int n = 0; n < 4; n++)
        acc[m][n] = __builtin_amdgcn_mfma_f32_16x16x32_bf16(af[m], bf[n], acc[m][n], 0, 0, 0);
  }
}

// ---------------- QKV GEMM + scatter epilogue (V stored transposed) ----------
__global__ __launch_bounds__(256) void qkv_gemm_kernel(const unsigned short* __restrict__ A,
                                                       const unsigned short* __restrict__ Bt,
                                                       unsigned short* __restrict__ qb,
                                                       unsigned short* __restrict__ kb,
                                                       unsigned short* __restrict__ vtb) {
  __shared__ unsigned short sA[BM * BKT];
  __shared__ unsigned short sB[BN * BKT];
  const int nbn = NQKV / BN;  // 24
  const int bm = blockIdx.x / nbn, bn = blockIdx.x % nbn;
  f32x4 acc[4][4];
  gemm_core(A, Bt, DMODEL, bm * BM, bn * BN, sA, sB, acc);
  const int t = threadIdx.x, lane = t & 63, wave = t >> 6;
  const int l15 = lane & 15, g = lane >> 4;
  const int wr = (wave >> 1) * 64, wc = (wave & 1) * 64;
#pragma unroll
  for (int m = 0; m < 4; m++)
#pragma unroll
    for (int n = 0; n < 4; n++) {
      const int col = bn * BN + wc + n * 16 + l15;
      const int part = col >> 10;
      const int h = (col >> 6) & 15;
      const int d = col & 63;
      const int row0 = bm * BM + wr + m * 16 + 4 * g;
      const int bb = row0 >> 11, i0 = row0 & 2047;
      if (part == 2) {
        // V^T layout: [b*16+h][d][n] -- 4 consecutive i values vectorize
        union { short4v v; unsigned short u[4]; } pk;
#pragma unroll
        for (int r = 0; r < 4; r++) pk.u[r] = f2bf(acc[m][n][r]);
        *(short4v*)(vtb + ((size_t)(bb * NHEAD + h) * DHEAD + d) * SEQ + i0) = pk.v;
      } else {
#pragma unroll
        for (int r = 0; r < 4; r++) {
          const size_t idx = (((size_t)(bb * NHEAD + h)) * SEQ + i0 + r) * DHEAD + d;
          const float v = acc[m][n][r];
          if (part == 0) qb[idx] = f2bf(v * 0.125f);  // q * d^-0.5
          else kb[idx] = f2bf(v);
        }
      }
    }
}

// ---------------- output GEMM: d_out = attn_out @ w_out ----------------------
__global__ __launch_bounds__(256) void out_gemm_kernel(const unsigned short* __restrict__ A,
                                                       const unsigned short* __restrict__ Bt,
                                                       float* __restrict__ C) {
  __shared__ unsigned short sA[BM * BKT];
  __shared__ unsigned short sB[BN * BKT];
  const int nbn = DMODEL / BN;  // 8
  const int bm = blockIdx.x / nbn, bn = blockIdx.x % nbn;
  f32x4 acc[4][4];
  gemm_core(A, Bt, DINNER, bm * BM, bn * BN, sA, sB, acc);
  const int t = threadIdx.x, lane = t & 63, wave = t >> 6;
  const int l15 = lane & 15, g = lane >> 4;
  const int wr = (wave >> 1) * 64, wc = (wave & 1) * 64;
#pragma unroll
  for (int m = 0; m < 4; m++)
#pragma unroll
    for (int n = 0; n < 4; n++) {
      const int col = bn * BN + wc + n * 16 + l15;
#pragma unroll
      for (int r = 0; r < 4; r++) {
        const int row = bm * BM + wr + m * 16 + 4 * g + r;
        C[(size_t)row * DMODEL + col] = acc[m][n][r];
      }
    }
}

// ---------------- causal flash attention: wave-independent, zero-barrier -----
// Each wave owns a 32-row q-tile. Swapped QK^T (mfma(K,Q)) makes softmax rows
// 4-lane-local and P lands in registers already in PV A-fragment layout.
// K read row-major [bh][n][d]; V read from the transposed [bh][d][n] buffer.
__global__ __launch_bounds__(256) void attn_kernel(const unsigned short* __restrict__ qb,
                                                   const unsigned short* __restrict__ kb,
                                                   const unsigned short* __restrict__ vtb,
                                                   unsigned short* __restrict__ ob) {
  const int t = threadIdx.x, lane = t & 63, wave = t >> 6;
  const int l15 = lane & 15, g = lane >> 4;
  const int bh = blockIdx.x & 31;  // b*16+h
  const int p = blockIdx.x >> 5;   // 0..15
  // balanced causal tiles: work(tile j) = j+1; sum = 130 per block
  const int tile = (wave == 0) ? p : (wave == 1) ? 63 - p : (wave == 2) ? 31 - p : 32 + p;
  const int wq0 = tile * 32;
  const unsigned short* qptr = qb + (size_t)bh * SEQ * DHEAD;
  const unsigned short* kptr = kb + (size_t)bh * SEQ * DHEAD;
  const unsigned short* vtptr = vtb + (size_t)bh * DHEAD * SEQ;

  // Q fragments (B operand): [qh][kk], row l15 = q, elems = d
  short8v qf[2][2];
#pragma unroll
  for (int qh = 0; qh < 2; qh++)
#pragma unroll
    for (int kk = 0; kk < 2; kk++) {
      const unsigned short* pq = qptr + (size_t)(wq0 + qh * 16 + l15) * DHEAD + kk * 32 + 4 * g;
      qf[qh][kk] = load_frag(pq, pq + 16);
    }

  float rm[2], rl[2];
  f32x4 acc_o[2][4];
#pragma unroll
  for (int qh = 0; qh < 2; qh++) {
    rm[qh] = -__builtin_inff();
    rl[qh] = 0.f;
#pragma unroll
    for (int df = 0; df < 4; df++) acc_o[qh][df] = (f32x4){0.f, 0.f, 0.f, 0.f};
  }

  const int nk = wq0 / 32 + 1;
  for (int kt = 0; kt < nk; kt++) {
    const int k0 = kt * 32;
    // K fragments (A operand): row l15 = key, elems = d
    short8v kf[2][2];
#pragma unroll
    for (int n = 0; n < 2; n++)
#pragma unroll
      for (int kk = 0; kk < 2; kk++) {
        const unsigned short* pk = kptr + (size_t)(k0 + n * 16 + l15) * DHEAD + kk * 32 + 4 * g;
        kf[n][kk] = load_frag(pk, pk + 16);
      }
    // V^T fragments (B operand for PV): row l15 = d, elems = key
    short8v vf[4];
#pragma unroll
    for (int df = 0; df < 4; df++) {
      const unsigned short* pv = vtptr + (size_t)(df * 16 + l15) * SEQ + k0 + 4 * g;
      vf[df] = load_frag(pv, pv + 16);
    }
    // QK^T swapped: s[qh][n] = D[key][q], key = k0+n*16+4g+r, q = wq0+qh*16+l15
    f32x4 s[2][2];
#pragma unroll
    for (int qh = 0; qh < 2; qh++)
#pragma unroll
      for (int n = 0; n < 2; n++) s[qh][n] = (f32x4){0.f, 0.f, 0.f, 0.f};
#pragma unroll
    for (int qh = 0; qh < 2; qh++)
#pragma unroll
      for (int n = 0; n < 2; n++)
#pragma unroll
        for (int kk = 0; kk < 2; kk++)
          s[qh][n] = __builtin_amdgcn_mfma_f32_16x16x32_bf16(kf[n][kk], qf[qh][kk], s[qh][n], 0, 0, 0);

    short8v pa[2];
#pragma unroll
    for (int qh = 0; qh < 2; qh++) {
      const int qrow = wq0 + qh * 16 + l15;
      float mx = -__builtin_inff();
#pragma unroll
      for (int n = 0; n < 2; n++)
#pragma unroll
        for (int r = 0; r < 4; r++) {
          const int key = k0 + n * 16 + 4 * g + r;
          float v = s[qh][n][r];
          v = (key > qrow) ? -__builtin_inff() : v;
          s[qh][n][r] = v;
          mx = fmaxf(mx, v);
        }
      mx = fmaxf(mx, __shfl_xor(mx, 16));
      mx = fmaxf(mx, __shfl_xor(mx, 32));
      const float nm = fmaxf(rm[qh], mx);
      const float alpha = __expf(rm[qh] - nm);
      rm[qh] = nm;
      float ps = 0.f;
#pragma unroll
      for (int n = 0; n < 2; n++)
#pragma unroll
        for (int r = 0; r < 4; r++) {
          const float e = __expf(s[qh][n][r] - nm);
          s[qh][n][r] = e;
          ps += e;
        }
      ps += __shfl_xor(ps, 16);
      ps += __shfl_xor(ps, 32);
      rl[qh] = rl[qh] * alpha + ps;
      // rescale O: row index in acc space is 4g+r; alpha lives at lane l15=row
#pragma unroll
      for (int r = 0; r < 4; r++) {
        const float al = __shfl(alpha, 4 * g + r);
#pragma unroll
        for (int df = 0; df < 4; df++) acc_o[qh][df][r] *= al;
      }
      // P already in A-fragment layout: slots 0..3 = keys 4g+j, 4..7 = 16+4g+j
      union { short8v v; unsigned short u[8]; } pu;
#pragma unroll
      for (int j = 0; j < 4; j++) {
        pu.u[j] = f2bf(s[qh][0][j]);
        pu.u[j + 4] = f2bf(s[qh][1][j]);
      }
      pa[qh] = pu.v;
    }
#pragma unroll
    for (int qh = 0; qh < 2; qh++)
#pragma unroll
      for (int df = 0; df < 4; df++)
        acc_o[qh][df] = __builtin_amdgcn_mfma_f32_16x16x32_bf16(pa[qh], vf[df], acc_o[qh][df], 0, 0, 0);
  }

  // epilogue: ob[b][i][h*64+d] = O / l
  const int bb = bh >> 4, hh = bh & 15;
#pragma unroll
  for (int qh = 0; qh < 2; qh++) {
    const float inv = 1.0f / rl[qh];
#pragma unroll
    for (int r = 0; r < 4; r++) {
      const float iv = __shfl(inv, 4 * g + r);
      const int i = wq0 + qh * 16 + 4 * g + r;
#pragma unroll
      for (int df = 0; df < 4; df++) {
        ob[((size_t)bb * SEQ + i) * DINNER + hh * DHEAD + df * 16 + l15] =
            f2bf(acc_o[qh][df][r] * iv);
      }
    }
  }
}

extern "C" void kernel_launch(void* const* d_in, const int* in_sizes, int n_in,
                              void* d_out, int out_size, void* d_ws, size_t ws_size,
                              hipStream_t stream) {
  (void)in_sizes; (void)n_in; (void)out_size; (void)ws_size;
  const float* x = (const float*)d_in[0];
  const float* gamma = (const float*)d_in[1];
  const float* w_qkv = (const float*)d_in[2];
  const float* w_out = (const float*)d_in[3];
  float* out = (float*)d_out;
  char* ws = (char*)d_ws;
  unsigned short* wqkvT = (unsigned short*)(ws);                // 6291456 B
  unsigned short* woutT = (unsigned short*)(ws + 6291456);      // 2097152 B
  unsigned short* normed = (unsigned short*)(ws + 8388608);     // 8388608 B
  unsigned short* qbuf = (unsigned short*)(ws + 16777216);      // 8388608 B
  unsigned short* kbuf = (unsigned short*)(ws + 25165824);      // 8388608 B
  unsigned short* vtbuf = (unsigned short*)(ws + 33554432);     // 8388608 B (transposed V)
  unsigned short* aout = (unsigned short*)(ws + 41943040);      // 8388608 B

  hipLaunchKernelGGL(transpose_cast_kernel, dim3((DMODEL / 32) * (NQKV / 32)), dim3(256), 0,
                     stream, w_qkv, wqkvT, DMODEL, NQKV);
  hipLaunchKernelGGL(transpose_cast_kernel, dim3((DINNER / 32) * (DMODEL / 32)), dim3(256), 0,
                     stream, w_out, woutT, DINNER, DMODEL);
  hipLaunchKernelGGL(rmsnorm_kernel, dim3(BATCH * SEQ), dim3(256), 0, stream, x, gamma, normed);
  hipLaunchKernelGGL(qkv_gemm_kernel, dim3((BATCH * SEQ / BM) * (NQKV / BN)), dim3(256), 0,
                     stream, normed, wqkvT, qbuf, kbuf, vtbuf);
  hipLaunchKernelGGL(attn_kernel, dim3(BATCH * NHEAD * 16), dim3(256), 0, stream,
                     qbuf, kbuf, vtbuf, aout);
  hipLaunchKernelGGL(out_gemm_kernel, dim3((BATCH * SEQ / BM) * (DMODEL / BN)), dim3(256), 0,
                     stream, aout, woutT, out);
}

// Round 3
// 193.507 us; speedup vs baseline: 1.7440x; 1.6844x over previous
//
#include <hip/hip_runtime.h>
#include <hip/hip_bf16.h>

#define BATCH 2
#define SEQ 2048
#define DMODEL 1024
#define NHEAD 16
#define DHEAD 64
#define NQKV 3072
#define DINNER 1024

typedef __attribute__((ext_vector_type(4))) short short4v;
typedef __attribute__((ext_vector_type(8))) short short8v;
typedef __attribute__((ext_vector_type(4))) float f32x4;

__device__ __forceinline__ unsigned short f2bf(float f) {
  union { float f; unsigned int u; } c; c.f = f;
  unsigned int u = c.u;
  u += 0x7fffu + ((u >> 16) & 1u);
  return (unsigned short)(u >> 16);
}

__device__ __forceinline__ short8v load_frag(const unsigned short* p0, const unsigned short* p1) {
  union { short8v v8; short4v v4[2]; } u;
  u.v4[0] = *(const short4v*)p0;
  u.v4[1] = *(const short4v*)p1;
  return u.v8;
}

#define GL16(gp, lp)                                             \
  __builtin_amdgcn_global_load_lds(                              \
      (__attribute__((address_space(1))) void*)(gp),             \
      (__attribute__((address_space(3))) void*)(lp), 16, 0, 0)

// ---------------- transpose + cast fp32 [K][N] -> bf16 [N][K] ----------------
__global__ __launch_bounds__(256) void transpose_cast_kernel(const float* __restrict__ in,
                                                             unsigned short* __restrict__ out,
                                                             int K, int N) {
  __shared__ float tile[32][33];
  const int tiles_n = N >> 5;
  const int tn = blockIdx.x % tiles_n;
  const int tk = blockIdx.x / tiles_n;
  const int k0 = tk << 5, n0 = tn << 5;
  const int t = threadIdx.x;
#pragma unroll
  for (int p = 0; p < 4; p++) {
    const int e = p * 256 + t;
    const int r = e >> 5, c = e & 31;
    tile[r][c] = in[(size_t)(k0 + r) * N + n0 + c];
  }
  __syncthreads();
#pragma unroll
  for (int p = 0; p < 4; p++) {
    const int e = p * 256 + t;
    const int r = e >> 5, c = e & 31;
    out[(size_t)(n0 + r) * K + k0 + c] = f2bf(tile[c][r]);
  }
}

// ---------------- RMSNorm (F.normalize * sqrt(dim) * gamma) -> bf16 ----------
__global__ __launch_bounds__(256) void rmsnorm_kernel(const float* __restrict__ x,
                                                      const float* __restrict__ gamma,
                                                      unsigned short* __restrict__ out) {
  const int row = blockIdx.x;
  const int t = threadIdx.x;
  const float* xr = x + (size_t)row * DMODEL;
  float4 v = ((const float4*)xr)[t];
  float ss = v.x * v.x + v.y * v.y + v.z * v.z + v.w * v.w;
#pragma unroll
  for (int off = 1; off < 64; off <<= 1) ss += __shfl_xor(ss, off);
  __shared__ float wss[4];
  if ((t & 63) == 0) wss[t >> 6] = ss;
  __syncthreads();
  const float tot = wss[0] + wss[1] + wss[2] + wss[3];
  float l2 = sqrtf(tot);
  l2 = fmaxf(l2, 1e-12f);
  const float s = 32.0f / l2;  // sqrt(1024)/l2
  const float4 gm = ((const float4*)gamma)[t];
  unsigned short o[4];
  o[0] = f2bf(v.x * s * gm.x);
  o[1] = f2bf(v.y * s * gm.y);
  o[2] = f2bf(v.z * s * gm.z);
  o[3] = f2bf(v.w * s * gm.w);
  unsigned short* op = out + (size_t)row * DMODEL + t * 4;
  *(short4v*)op = *(short4v*)o;
}

// ---------------- shared GEMM core (m97 structure): global_load_lds, linear LDS,
// contiguous 16B fragments (k-slot map = 8g..8g+7, identical for A and B).
#define BM 128
#define BN 128
#define BKT 32

__device__ void gemm_core(const unsigned short* __restrict__ A,
                          const unsigned short* __restrict__ Bt, int K, int rowBase,
                          int colBase, unsigned short* sA, unsigned short* sB,
                          f32x4 acc[4][4]) {
  const int t = threadIdx.x;
  const int lane = t & 63, wave = t >> 6;
  const int l15 = lane & 15, g = lane >> 4;
  const int wr = (wave >> 1) * 64, wc = (wave & 1) * 64;
#pragma unroll
  for (int m = 0; m < 4; m++)
#pragma unroll
    for (int n = 0; n < 4; n++) acc[m][n] = (f32x4){0.f, 0.f, 0.f, 0.f};
  // staging: tile [128][32] shorts = 8KB = 512 x 16B chunks; thread t covers
  // chunks t and t+256. chunk c: row = c>>2, col-offset = (c&3)*8 shorts.
  const int r0 = t >> 2, o0 = (t & 3) * 8;
  const unsigned short* Ag0 = A + (size_t)(rowBase + r0) * K + o0;
  const unsigned short* Ag1 = A + (size_t)(rowBase + r0 + 64) * K + o0;
  const unsigned short* Bg0 = Bt + (size_t)(colBase + r0) * K + o0;
  const unsigned short* Bg1 = Bt + (size_t)(colBase + r0 + 64) * K + o0;
  unsigned short* sA0 = sA + t * 8;
  unsigned short* sA1 = sA + (t + 256) * 8;
  unsigned short* sB0 = sB + t * 8;
  unsigned short* sB1 = sB + (t + 256) * 8;
  for (int k0 = 0; k0 < K; k0 += BKT) {
    __syncthreads();
    GL16(Ag0 + k0, sA0);
    GL16(Ag1 + k0, sA1);
    GL16(Bg0 + k0, sB0);
    GL16(Bg1 + k0, sB1);
    asm volatile("s_waitcnt vmcnt(0)" ::: "memory");
    __syncthreads();
    short8v af[4], bf[4];
#pragma unroll
    for (int m = 0; m < 4; m++)
      af[m] = *(const short8v*)(sA + (wr + m * 16 + l15) * BKT + 8 * g);
#pragma unroll
    for (int n = 0; n < 4; n++)
      bf[n] = *(const short8v*)(sB + (wc + n * 16 + l15) * BKT + 8 * g);
#pragma unroll
    for (int m = 0; m < 4; m++)
#pragma unroll
      for (int n = 0; n < 4; n++)
        acc[m][n] = __builtin_amdgcn_mfma_f32_16x16x32_bf16(af[m], bf[n], acc[m][n], 0, 0, 0);
  }
}

// ---------------- QKV GEMM + scatter epilogue (V stored transposed) ----------
__global__ __launch_bounds__(256) void qkv_gemm_kernel(const unsigned short* __restrict__ A,
                                                       const unsigned short* __restrict__ Bt,
                                                       unsigned short* __restrict__ qb,
                                                       unsigned short* __restrict__ kb,
                                                       unsigned short* __restrict__ vtb) {
  __shared__ __align__(16) unsigned short sA[BM * BKT];
  __shared__ __align__(16) unsigned short sB[BN * BKT];
  const int nbn = NQKV / BN;  // 24
  const int bm = blockIdx.x / nbn, bn = blockIdx.x % nbn;
  f32x4 acc[4][4];
  gemm_core(A, Bt, DMODEL, bm * BM, bn * BN, sA, sB, acc);
  const int t = threadIdx.x, lane = t & 63, wave = t >> 6;
  const int l15 = lane & 15, g = lane >> 4;
  const int wr = (wave >> 1) * 64, wc = (wave & 1) * 64;
#pragma unroll
  for (int m = 0; m < 4; m++)
#pragma unroll
    for (int n = 0; n < 4; n++) {
      const int col = bn * BN + wc + n * 16 + l15;
      const int part = col >> 10;
      const int h = (col >> 6) & 15;
      const int d = col & 63;
      const int row0 = bm * BM + wr + m * 16 + 4 * g;
      const int bb = row0 >> 11, i0 = row0 & 2047;
      if (part == 2) {
        // V^T layout: [b*16+h][d][n] -- 4 consecutive i values vectorize
        union { short4v v; unsigned short u[4]; } pk;
#pragma unroll
        for (int r = 0; r < 4; r++) pk.u[r] = f2bf(acc[m][n][r]);
        *(short4v*)(vtb + ((size_t)(bb * NHEAD + h) * DHEAD + d) * SEQ + i0) = pk.v;
      } else {
#pragma unroll
        for (int r = 0; r < 4; r++) {
          const size_t idx = (((size_t)(bb * NHEAD + h)) * SEQ + i0 + r) * DHEAD + d;
          const float v = acc[m][n][r];
          if (part == 0) qb[idx] = f2bf(v * 0.125f);  // q * d^-0.5
          else kb[idx] = f2bf(v);
        }
      }
    }
}

// ---------------- output GEMM: d_out = attn_out @ w_out ----------------------
__global__ __launch_bounds__(256) void out_gemm_kernel(const unsigned short* __restrict__ A,
                                                       const unsigned short* __restrict__ Bt,
                                                       float* __restrict__ C) {
  __shared__ __align__(16) unsigned short sA[BM * BKT];
  __shared__ __align__(16) unsigned short sB[BN * BKT];
  const int nbn = DMODEL / BN;  // 8
  const int bm = blockIdx.x / nbn, bn = blockIdx.x % nbn;
  f32x4 acc[4][4];
  gemm_core(A, Bt, DINNER, bm * BM, bn * BN, sA, sB, acc);
  const int t = threadIdx.x, lane = t & 63, wave = t >> 6;
  const int l15 = lane & 15, g = lane >> 4;
  const int wr = (wave >> 1) * 64, wc = (wave & 1) * 64;
#pragma unroll
  for (int m = 0; m < 4; m++)
#pragma unroll
    for (int n = 0; n < 4; n++) {
      const int col = bn * BN + wc + n * 16 + l15;
#pragma unroll
      for (int r = 0; r < 4; r++) {
        const int row = bm * BM + wr + m * 16 + 4 * g + r;
        C[(size_t)row * DMODEL + col] = acc[m][n][r];
      }
    }
}

// ---------------- causal flash attention: wave-independent, zero-barrier -----
// Each wave owns a 32-row q-tile. Swapped QK^T (mfma(K,Q)) makes softmax rows
// 4-lane-local and P lands in registers already in PV A-fragment layout.
// Q/K use contiguous 16B fragments (same k-map both operands); V^T keeps the
// split (4g / 16+4g) layout to match P's MFMA-output slot order.
__global__ __launch_bounds__(256) void attn_kernel(const unsigned short* __restrict__ qb,
                                                   const unsigned short* __restrict__ kb,
                                                   const unsigned short* __restrict__ vtb,
                                                   unsigned short* __restrict__ ob) {
  const int t = threadIdx.x, lane = t & 63, wave = t >> 6;
  const int l15 = lane & 15, g = lane >> 4;
  const int bh = blockIdx.x & 31;  // b*16+h
  const int p = blockIdx.x >> 5;   // 0..15
  // balanced causal tiles: work(tile j) = j+1; sum = 130 per block
  const int tile = (wave == 0) ? p : (wave == 1) ? 63 - p : (wave == 2) ? 31 - p : 32 + p;
  const int wq0 = tile * 32;
  const unsigned short* qptr = qb + (size_t)bh * SEQ * DHEAD;
  const unsigned short* kptr = kb + (size_t)bh * SEQ * DHEAD;
  const unsigned short* vtptr = vtb + (size_t)bh * DHEAD * SEQ;

  // Q fragments (B operand): [qh][kk], row l15 = q, elems = d (contiguous 8)
  short8v qf[2][2];
#pragma unroll
  for (int qh = 0; qh < 2; qh++)
#pragma unroll
    for (int kk = 0; kk < 2; kk++)
      qf[qh][kk] = *(const short8v*)(qptr + (size_t)(wq0 + qh * 16 + l15) * DHEAD +
                                     kk * 32 + 8 * g);

  float rm[2], rl[2];
  f32x4 acc_o[2][4];
#pragma unroll
  for (int qh = 0; qh < 2; qh++) {
    rm[qh] = -__builtin_inff();
    rl[qh] = 0.f;
#pragma unroll
    for (int df = 0; df < 4; df++) acc_o[qh][df] = (f32x4){0.f, 0.f, 0.f, 0.f};
  }

  const int nk = wq0 / 32 + 1;
  for (int kt = 0; kt < nk; kt++) {
    const int k0 = kt * 32;
    // K fragments (A operand): row l15 = key, elems = d (contiguous 8)
    short8v kf[2][2];
#pragma unroll
    for (int n = 0; n < 2; n++)
#pragma unroll
      for (int kk = 0; kk < 2; kk++)
        kf[n][kk] = *(const short8v*)(kptr + (size_t)(k0 + n * 16 + l15) * DHEAD +
                                      kk * 32 + 8 * g);
    // V^T fragments (B operand for PV): row l15 = d, elems = key
    short8v vf[4];
#pragma unroll
    for (int df = 0; df < 4; df++) {
      const unsigned short* pv = vtptr + (size_t)(df * 16 + l15) * SEQ + k0 + 4 * g;
      vf[df] = load_frag(pv, pv + 16);
    }
    // QK^T swapped: s[qh][n] = D[key][q], key = k0+n*16+4g+r, q = wq0+qh*16+l15
    f32x4 s[2][2];
#pragma unroll
    for (int qh = 0; qh < 2; qh++)
#pragma unroll
      for (int n = 0; n < 2; n++) s[qh][n] = (f32x4){0.f, 0.f, 0.f, 0.f};
#pragma unroll
    for (int qh = 0; qh < 2; qh++)
#pragma unroll
      for (int n = 0; n < 2; n++)
#pragma unroll
        for (int kk = 0; kk < 2; kk++)
          s[qh][n] = __builtin_amdgcn_mfma_f32_16x16x32_bf16(kf[n][kk], qf[qh][kk], s[qh][n], 0, 0, 0);

    short8v pa[2];
#pragma unroll
    for (int qh = 0; qh < 2; qh++) {
      const int qrow = wq0 + qh * 16 + l15;
      float mx = -__builtin_inff();
#pragma unroll
      for (int n = 0; n < 2; n++)
#pragma unroll
        for (int r = 0; r < 4; r++) {
          const int key = k0 + n * 16 + 4 * g + r;
          float v = s[qh][n][r];
          v = (key > qrow) ? -__builtin_inff() : v;
          s[qh][n][r] = v;
          mx = fmaxf(mx, v);
        }
      mx = fmaxf(mx, __shfl_xor(mx, 16));
      mx = fmaxf(mx, __shfl_xor(mx, 32));
      const float nm = fmaxf(rm[qh], mx);
      const float alpha = __expf(rm[qh] - nm);
      rm[qh] = nm;
      float ps = 0.f;
#pragma unroll
      for (int n = 0; n < 2; n++)
#pragma unroll
        for (int r = 0; r < 4; r++) {
          const float e = __expf(s[qh][n][r] - nm);
          s[qh][n][r] = e;
          ps += e;
        }
      ps += __shfl_xor(ps, 16);
      ps += __shfl_xor(ps, 32);
      rl[qh] = rl[qh] * alpha + ps;
      // rescale O: row index in acc space is 4g+r; alpha lives at lane l15=row
#pragma unroll
      for (int r = 0; r < 4; r++) {
        const float al = __shfl(alpha, 4 * g + r);
#pragma unroll
        for (int df = 0; df < 4; df++) acc_o[qh][df][r] *= al;
      }
      // P already in A-fragment layout: slots 0..3 = keys 4g+j, 4..7 = 16+4g+j
      union { short8v v; unsigned short u[8]; } pu;
#pragma unroll
      for (int j = 0; j < 4; j++) {
        pu.u[j] = f2bf(s[qh][0][j]);
        pu.u[j + 4] = f2bf(s[qh][1][j]);
      }
      pa[qh] = pu.v;
    }
#pragma unroll
    for (int qh = 0; qh < 2; qh++)
#pragma unroll
      for (int df = 0; df < 4; df++)
        acc_o[qh][df] = __builtin_amdgcn_mfma_f32_16x16x32_bf16(pa[qh], vf[df], acc_o[qh][df], 0, 0, 0);
  }

  // epilogue: ob[b][i][h*64+d] = O / l
  const int bb = bh >> 4, hh = bh & 15;
#pragma unroll
  for (int qh = 0; qh < 2; qh++) {
    const float inv = 1.0f / rl[qh];
#pragma unroll
    for (int r = 0; r < 4; r++) {
      const float iv = __shfl(inv, 4 * g + r);
      const int i = wq0 + qh * 16 + 4 * g + r;
#pragma unroll
      for (int df = 0; df < 4; df++) {
        ob[((size_t)bb * SEQ + i) * DINNER + hh * DHEAD + df * 16 + l15] =
            f2bf(acc_o[qh][df][r] * iv);
      }
    }
  }
}

extern "C" void kernel_launch(void* const* d_in, const int* in_sizes, int n_in,
                              void* d_out, int out_size, void* d_ws, size_t ws_size,
                              hipStream_t stream) {
  (void)in_sizes; (void)n_in; (void)out_size; (void)ws_size;
  const float* x = (const float*)d_in[0];
  const float* gamma = (const float*)d_in[1];
  const float* w_qkv = (const float*)d_in[2];
  const float* w_out = (const float*)d_in[3];
  float* out = (float*)d_out;
  char* ws = (char*)d_ws;
  unsigned short* wqkvT = (unsigned short*)(ws);                // 6291456 B
  unsigned short* woutT = (unsigned short*)(ws + 6291456);      // 2097152 B
  unsigned short* normed = (unsigned short*)(ws + 8388608);     // 8388608 B
  unsigned short* qbuf = (unsigned short*)(ws + 16777216);      // 8388608 B
  unsigned short* kbuf = (unsigned short*)(ws + 25165824);      // 8388608 B
  unsigned short* vtbuf = (unsigned short*)(ws + 33554432);     // 8388608 B (transposed V)
  unsigned short* aout = (unsigned short*)(ws + 41943040);      // 8388608 B

  hipLaunchKernelGGL(transpose_cast_kernel, dim3((DMODEL / 32) * (NQKV / 32)), dim3(256), 0,
                     stream, w_qkv, wqkvT, DMODEL, NQKV);
  hipLaunchKernelGGL(transpose_cast_kernel, dim3((DINNER / 32) * (DMODEL / 32)), dim3(256), 0,
                     stream, w_out, woutT, DINNER, DMODEL);
  hipLaunchKernelGGL(rmsnorm_kernel, dim3(BATCH * SEQ), dim3(256), 0, stream, x, gamma, normed);
  hipLaunchKernelGGL(qkv_gemm_kernel, dim3((BATCH * SEQ / BM) * (NQKV / BN)), dim3(256), 0,
                     stream, normed, wqkvT, qbuf, kbuf, vtbuf);
  hipLaunchKernelGGL(attn_kernel, dim3(BATCH * NHEAD * 16), dim3(256), 0, stream,
                     qbuf, kbuf, vtbuf, aout);
  hipLaunchKernelGGL(out_gemm_kernel, dim3((BATCH * SEQ / BM) * (DMODEL / BN)), dim3(256), 0,
                     stream, aout, woutT, out);
}

// Round 4
// 189.024 us; speedup vs baseline: 1.7854x; 1.0237x over previous
//
#include <hip/hip_runtime.h>
#include <hip/hip_bf16.h>

#define BATCH 2
#define SEQ 2048
#define DMODEL 1024
#define NHEAD 16
#define DHEAD 64
#define NQKV 3072
#define DINNER 1024

typedef __attribute__((ext_vector_type(4))) short short4v;
typedef __attribute__((ext_vector_type(8))) short short8v;
typedef __attribute__((ext_vector_type(4))) float f32x4;

__device__ __forceinline__ unsigned short f2bf(float f) {
  union { float f; unsigned int u; } c; c.f = f;
  unsigned int u = c.u;
  u += 0x7fffu + ((u >> 16) & 1u);
  return (unsigned short)(u >> 16);
}

__device__ __forceinline__ short8v load_frag(const unsigned short* p0, const unsigned short* p1) {
  union { short8v v8; short4v v4[2]; } u;
  u.v4[0] = *(const short4v*)p0;
  u.v4[1] = *(const short4v*)p1;
  return u.v8;
}

#define GL16(gp, lp)                                             \
  __builtin_amdgcn_global_load_lds(                              \
      (__attribute__((address_space(1))) void*)(gp),             \
      (__attribute__((address_space(3))) void*)(lp), 16, 0, 0)

// ---------------- transpose + cast fp32 [K][N] -> bf16 [N][K] ----------------
__global__ __launch_bounds__(256) void transpose_cast_kernel(const float* __restrict__ in,
                                                             unsigned short* __restrict__ out,
                                                             int K, int N) {
  __shared__ float tile[32][33];
  const int tiles_n = N >> 5;
  const int tn = blockIdx.x % tiles_n;
  const int tk = blockIdx.x / tiles_n;
  const int k0 = tk << 5, n0 = tn << 5;
  const int t = threadIdx.x;
#pragma unroll
  for (int p = 0; p < 4; p++) {
    const int e = p * 256 + t;
    const int r = e >> 5, c = e & 31;
    tile[r][c] = in[(size_t)(k0 + r) * N + n0 + c];
  }
  __syncthreads();
#pragma unroll
  for (int p = 0; p < 4; p++) {
    const int e = p * 256 + t;
    const int r = e >> 5, c = e & 31;
    out[(size_t)(n0 + r) * K + k0 + c] = f2bf(tile[c][r]);
  }
}

// ---------------- RMSNorm (F.normalize * sqrt(dim) * gamma) -> bf16 ----------
__global__ __launch_bounds__(256) void rmsnorm_kernel(const float* __restrict__ x,
                                                      const float* __restrict__ gamma,
                                                      unsigned short* __restrict__ out) {
  const int row = blockIdx.x;
  const int t = threadIdx.x;
  const float* xr = x + (size_t)row * DMODEL;
  float4 v = ((const float4*)xr)[t];
  float ss = v.x * v.x + v.y * v.y + v.z * v.z + v.w * v.w;
#pragma unroll
  for (int off = 1; off < 64; off <<= 1) ss += __shfl_xor(ss, off);
  __shared__ float wss[4];
  if ((t & 63) == 0) wss[t >> 6] = ss;
  __syncthreads();
  const float tot = wss[0] + wss[1] + wss[2] + wss[3];
  float l2 = sqrtf(tot);
  l2 = fmaxf(l2, 1e-12f);
  const float s = 32.0f / l2;  // sqrt(1024)/l2
  const float4 gm = ((const float4*)gamma)[t];
  unsigned short o[4];
  o[0] = f2bf(v.x * s * gm.x);
  o[1] = f2bf(v.y * s * gm.y);
  o[2] = f2bf(v.z * s * gm.z);
  o[3] = f2bf(v.w * s * gm.w);
  unsigned short* op = out + (size_t)row * DMODEL + t * 4;
  *(short4v*)op = *(short4v*)o;
}

// ---------------- shared GEMM core (m97 structure): global_load_lds, linear LDS,
// contiguous 16B fragments (k-slot map = 8g..8g+7, identical for A and B).
#define BM 128
#define BN 128
#define BKT 32

__device__ void gemm_core(const unsigned short* __restrict__ A,
                          const unsigned short* __restrict__ Bt, int K, int rowBase,
                          int colBase, unsigned short* sA, unsigned short* sB,
                          f32x4 acc[4][4]) {
  const int t = threadIdx.x;
  const int lane = t & 63, wave = t >> 6;
  const int l15 = lane & 15, g = lane >> 4;
  const int wr = (wave >> 1) * 64, wc = (wave & 1) * 64;
#pragma unroll
  for (int m = 0; m < 4; m++)
#pragma unroll
    for (int n = 0; n < 4; n++) acc[m][n] = (f32x4){0.f, 0.f, 0.f, 0.f};
  const int r0 = t >> 2, o0 = (t & 3) * 8;
  const unsigned short* Ag0 = A + (size_t)(rowBase + r0) * K + o0;
  const unsigned short* Ag1 = A + (size_t)(rowBase + r0 + 64) * K + o0;
  const unsigned short* Bg0 = Bt + (size_t)(colBase + r0) * K + o0;
  const unsigned short* Bg1 = Bt + (size_t)(colBase + r0 + 64) * K + o0;
  unsigned short* sA0 = sA + t * 8;
  unsigned short* sA1 = sA + (t + 256) * 8;
  unsigned short* sB0 = sB + t * 8;
  unsigned short* sB1 = sB + (t + 256) * 8;
  for (int k0 = 0; k0 < K; k0 += BKT) {
    __syncthreads();
    GL16(Ag0 + k0, sA0);
    GL16(Ag1 + k0, sA1);
    GL16(Bg0 + k0, sB0);
    GL16(Bg1 + k0, sB1);
    asm volatile("s_waitcnt vmcnt(0)" ::: "memory");
    __syncthreads();
    short8v af[4], bf[4];
#pragma unroll
    for (int m = 0; m < 4; m++)
      af[m] = *(const short8v*)(sA + (wr + m * 16 + l15) * BKT + 8 * g);
#pragma unroll
    for (int n = 0; n < 4; n++)
      bf[n] = *(const short8v*)(sB + (wc + n * 16 + l15) * BKT + 8 * g);
#pragma unroll
    for (int m = 0; m < 4; m++)
#pragma unroll
      for (int n = 0; n < 4; n++)
        acc[m][n] = __builtin_amdgcn_mfma_f32_16x16x32_bf16(af[m], bf[n], acc[m][n], 0, 0, 0);
  }
}

// ---------------- QKV GEMM + scatter epilogue (V stored transposed) ----------
__global__ __launch_bounds__(256) void qkv_gemm_kernel(const unsigned short* __restrict__ A,
                                                       const unsigned short* __restrict__ Bt,
                                                       unsigned short* __restrict__ qb,
                                                       unsigned short* __restrict__ kb,
                                                       unsigned short* __restrict__ vtb) {
  __shared__ __align__(16) unsigned short sA[BM * BKT];
  __shared__ __align__(16) unsigned short sB[BN * BKT];
  const int nbn = NQKV / BN;  // 24
  const int bm = blockIdx.x / nbn, bn = blockIdx.x % nbn;
  f32x4 acc[4][4];
  gemm_core(A, Bt, DMODEL, bm * BM, bn * BN, sA, sB, acc);
  const int t = threadIdx.x, lane = t & 63, wave = t >> 6;
  const int l15 = lane & 15, g = lane >> 4;
  const int wr = (wave >> 1) * 64, wc = (wave & 1) * 64;
#pragma unroll
  for (int m = 0; m < 4; m++)
#pragma unroll
    for (int n = 0; n < 4; n++) {
      const int col = bn * BN + wc + n * 16 + l15;
      const int part = col >> 10;
      const int h = (col >> 6) & 15;
      const int d = col & 63;
      const int row0 = bm * BM + wr + m * 16 + 4 * g;
      const int bb = row0 >> 11, i0 = row0 & 2047;
      if (part == 2) {
        // V^T layout: [b*16+h][d][n] -- 4 consecutive i values vectorize
        union { short4v v; unsigned short u[4]; } pk;
#pragma unroll
        for (int r = 0; r < 4; r++) pk.u[r] = f2bf(acc[m][n][r]);
        *(short4v*)(vtb + ((size_t)(bb * NHEAD + h) * DHEAD + d) * SEQ + i0) = pk.v;
      } else {
#pragma unroll
        for (int r = 0; r < 4; r++) {
          const size_t idx = (((size_t)(bb * NHEAD + h)) * SEQ + i0 + r) * DHEAD + d;
          const float v = acc[m][n][r];
          if (part == 0) qb[idx] = f2bf(v * 0.125f);  // q * d^-0.5
          else kb[idx] = f2bf(v);
        }
      }
    }
}

// ---------------- output GEMM: d_out = attn_out @ w_out ----------------------
__global__ __launch_bounds__(256) void out_gemm_kernel(const unsigned short* __restrict__ A,
                                                       const unsigned short* __restrict__ Bt,
                                                       float* __restrict__ C) {
  __shared__ __align__(16) unsigned short sA[BM * BKT];
  __shared__ __align__(16) unsigned short sB[BN * BKT];
  const int nbn = DMODEL / BN;  // 8
  const int bm = blockIdx.x / nbn, bn = blockIdx.x % nbn;
  f32x4 acc[4][4];
  gemm_core(A, Bt, DINNER, bm * BM, bn * BN, sA, sB, acc);
  const int t = threadIdx.x, lane = t & 63, wave = t >> 6;
  const int l15 = lane & 15, g = lane >> 4;
  const int wr = (wave >> 1) * 64, wc = (wave & 1) * 64;
#pragma unroll
  for (int m = 0; m < 4; m++)
#pragma unroll
    for (int n = 0; n < 4; n++) {
      const int col = bn * BN + wc + n * 16 + l15;
#pragma unroll
      for (int r = 0; r < 4; r++) {
        const int row = bm * BM + wr + m * 16 + 4 * g + r;
        C[(size_t)row * DMODEL + col] = acc[m][n][r];
      }
    }
}

// ---------------- causal flash attention: wave-independent, zero-barrier -----
// Swapped QK^T (mfma(K,Q)) AND swapped PV (mfma(Vt,P)): softmax state (m,l,
// alpha) and the O accumulator are both indexed col=q=l15 -> all rescales are
// lane-local (no cross-lane broadcasts). K/V register-double-buffered.
__global__ __launch_bounds__(256) void attn_kernel(const unsigned short* __restrict__ qb,
                                                   const unsigned short* __restrict__ kb,
                                                   const unsigned short* __restrict__ vtb,
                                                   unsigned short* __restrict__ ob) {
  const int t = threadIdx.x, lane = t & 63, wave = t >> 6;
  const int l15 = lane & 15, g = lane >> 4;
  const int bh = blockIdx.x & 31;  // b*16+h
  const int p = blockIdx.x >> 5;   // 0..15
  // balanced causal tiles: work(tile j) = j+1; sum = 130 per block
  const int tile = (wave == 0) ? p : (wave == 1) ? 63 - p : (wave == 2) ? 31 - p : 32 + p;
  const int wq0 = tile * 32;
  const unsigned short* qptr = qb + (size_t)bh * SEQ * DHEAD;
  const unsigned short* kptr = kb + (size_t)bh * SEQ * DHEAD;
  const unsigned short* vtptr = vtb + (size_t)bh * DHEAD * SEQ;

  // Q fragments (B operand): [qh][kk], l15 = q, elems = d (contiguous 8)
  short8v qf[2][2];
#pragma unroll
  for (int qh = 0; qh < 2; qh++)
#pragma unroll
    for (int kk = 0; kk < 2; kk++)
      qf[qh][kk] = *(const short8v*)(qptr + (size_t)(wq0 + qh * 16 + l15) * DHEAD +
                                     kk * 32 + 8 * g);

  float rm[2], rl[2];
  f32x4 acc_o[2][4];  // [qh][df]: col = q = l15, row(4g+r) = d = df*16+4g+r
#pragma unroll
  for (int qh = 0; qh < 2; qh++) {
    rm[qh] = -__builtin_inff();
    rl[qh] = 0.f;
#pragma unroll
    for (int df = 0; df < 4; df++) acc_o[qh][df] = (f32x4){0.f, 0.f, 0.f, 0.f};
  }

  const int nk = tile + 1;

#define LOADKV(kf, vf, kt_)                                                            \
  do {                                                                                 \
    const int k0_ = (kt_) * 32;                                                        \
    _Pragma("unroll") for (int n = 0; n < 2; n++)                                      \
        _Pragma("unroll") for (int kk = 0; kk < 2; kk++)                               \
            kf[n][kk] = *(const short8v*)(kptr + (size_t)(k0_ + n * 16 + l15) * DHEAD +\
                                          kk * 32 + 8 * g);                            \
    _Pragma("unroll") for (int df = 0; df < 4; df++) {                                 \
      const unsigned short* pv_ = vtptr + (size_t)(df * 16 + l15) * SEQ + k0_ + 4 * g; \
      vf[df] = load_frag(pv_, pv_ + 16);                                               \
    }                                                                                  \
  } while (0)

#define COMPUTE(kf, vf, kt_)                                                           \
  do {                                                                                 \
    const int k0_ = (kt_) * 32;                                                        \
    const bool diag_ = ((kt_) == tile);                                                \
    f32x4 s_[2][2];                                                                    \
    _Pragma("unroll") for (int qh = 0; qh < 2; qh++)                                   \
        _Pragma("unroll") for (int n = 0; n < 2; n++)                                  \
            s_[qh][n] = (f32x4){0.f, 0.f, 0.f, 0.f};                                   \
    _Pragma("unroll") for (int qh = 0; qh < 2; qh++)                                   \
        _Pragma("unroll") for (int n = 0; n < 2; n++)                                  \
            _Pragma("unroll") for (int kk = 0; kk < 2; kk++)                           \
                s_[qh][n] = __builtin_amdgcn_mfma_f32_16x16x32_bf16(                   \
                    kf[n][kk], qf[qh][kk], s_[qh][n], 0, 0, 0);                        \
    unsigned int pw_[2][4];                                                            \
    _Pragma("unroll") for (int qh = 0; qh < 2; qh++) {                                 \
      if (diag_) {                                                                     \
        const int qrow_ = wq0 + qh * 16 + l15;                                         \
        _Pragma("unroll") for (int n = 0; n < 2; n++)                                  \
            _Pragma("unroll") for (int r = 0; r < 4; r++) {                            \
          const int key_ = k0_ + n * 16 + 4 * g + r;                                   \
          if (key_ > qrow_) s_[qh][n][r] = -__builtin_inff();                          \
        }                                                                              \
      }                                                                                \
      float mx_ = s_[qh][0][0];                                                        \
      _Pragma("unroll") for (int n = 0; n < 2; n++)                                    \
          _Pragma("unroll") for (int r = 0; r < 4; r++)                                \
              if (n || r) mx_ = fmaxf(mx_, s_[qh][n][r]);                              \
      mx_ = fmaxf(mx_, __shfl_xor(mx_, 16));                                           \
      mx_ = fmaxf(mx_, __shfl_xor(mx_, 32));                                           \
      if (!__all(mx_ <= rm[qh])) {                                                     \
        const float nm_ = fmaxf(rm[qh], mx_);                                          \
        const float al_ = __expf(rm[qh] - nm_);                                        \
        rm[qh] = nm_;                                                                  \
        rl[qh] *= al_;                                                                 \
        _Pragma("unroll") for (int df = 0; df < 4; df++)                               \
            _Pragma("unroll") for (int r = 0; r < 4; r++) acc_o[qh][df][r] *= al_;     \
      }                                                                                \
      float ps_ = 0.f;                                                                 \
      _Pragma("unroll") for (int n = 0; n < 2; n++)                                    \
          _Pragma("unroll") for (int r = 0; r < 4; r++) {                              \
        const float e_ = __expf(s_[qh][n][r] - rm[qh]);                                \
        s_[qh][n][r] = e_;                                                             \
        ps_ += e_;                                                                     \
      }                                                                                \
      ps_ += __shfl_xor(ps_, 16);                                                      \
      ps_ += __shfl_xor(ps_, 32);                                                      \
      rl[qh] += ps_;                                                                   \
      asm("v_cvt_pk_bf16_f32 %0, %1, %2"                                               \
          : "=v"(pw_[qh][0]) : "v"(s_[qh][0][0]), "v"(s_[qh][0][1]));                  \
      asm("v_cvt_pk_bf16_f32 %0, %1, %2"                                               \
          : "=v"(pw_[qh][1]) : "v"(s_[qh][0][2]), "v"(s_[qh][0][3]));                  \
      asm("v_cvt_pk_bf16_f32 %0, %1, %2"                                               \
          : "=v"(pw_[qh][2]) : "v"(s_[qh][1][0]), "v"(s_[qh][1][1]));                  \
      asm("v_cvt_pk_bf16_f32 %0, %1, %2"                                               \
          : "=v"(pw_[qh][3]) : "v"(s_[qh][1][2]), "v"(s_[qh][1][3]));                  \
    }                                                                                  \
    _Pragma("unroll") for (int qh = 0; qh < 2; qh++) {                                 \
      union { short8v v; unsigned int w[4]; } pa_;                                     \
      pa_.w[0] = pw_[qh][0]; pa_.w[1] = pw_[qh][1];                                    \
      pa_.w[2] = pw_[qh][2]; pa_.w[3] = pw_[qh][3];                                    \
      _Pragma("unroll") for (int df = 0; df < 4; df++)                                 \
          acc_o[qh][df] = __builtin_amdgcn_mfma_f32_16x16x32_bf16(                     \
              vf[df], pa_.v, acc_o[qh][df], 0, 0, 0);                                  \
    }                                                                                  \
  } while (0)

  short8v kfA[2][2], vfA[4], kfB[2][2], vfB[4];
  LOADKV(kfA, vfA, 0);
  int kt = 0;
  for (; kt + 2 <= nk; kt += 2) {
    LOADKV(kfB, vfB, kt + 1);
    COMPUTE(kfA, vfA, kt);
    if (kt + 2 < nk) LOADKV(kfA, vfA, kt + 2);
    COMPUTE(kfB, vfB, kt + 1);
  }
  if (kt < nk) COMPUTE(kfA, vfA, kt);

  // epilogue: ob[b][q][h*64+d] = O / l ; q = l15 (lane-local inv, no shuffles)
  const int bb = bh >> 4, hh = bh & 15;
#pragma unroll
  for (int qh = 0; qh < 2; qh++) {
    const float inv = 1.0f / rl[qh];
    const int q = wq0 + qh * 16 + l15;
#pragma unroll
    for (int df = 0; df < 4; df++) {
      union { short4v v; unsigned short u[4]; } pk4;
#pragma unroll
      for (int r = 0; r < 4; r++) pk4.u[r] = f2bf(acc_o[qh][df][r] * inv);
      *(short4v*)(ob + ((size_t)bb * SEQ + q) * DINNER + hh * DHEAD + df * 16 + 4 * g) =
          pk4.v;
    }
  }
#undef LOADKV
#undef COMPUTE
}

extern "C" void kernel_launch(void* const* d_in, const int* in_sizes, int n_in,
                              void* d_out, int out_size, void* d_ws, size_t ws_size,
                              hipStream_t stream) {
  (void)in_sizes; (void)n_in; (void)out_size; (void)ws_size;
  const float* x = (const float*)d_in[0];
  const float* gamma = (const float*)d_in[1];
  const float* w_qkv = (const float*)d_in[2];
  const float* w_out = (const float*)d_in[3];
  float* out = (float*)d_out;
  char* ws = (char*)d_ws;
  unsigned short* wqkvT = (unsigned short*)(ws);                // 6291456 B
  unsigned short* woutT = (unsigned short*)(ws + 6291456);      // 2097152 B
  unsigned short* normed = (unsigned short*)(ws + 8388608);     // 8388608 B
  unsigned short* qbuf = (unsigned short*)(ws + 16777216);      // 8388608 B
  unsigned short* kbuf = (unsigned short*)(ws + 25165824);      // 8388608 B
  unsigned short* vtbuf = (unsigned short*)(ws + 33554432);     // 8388608 B (transposed V)
  unsigned short* aout = (unsigned short*)(ws + 41943040);      // 8388608 B

  hipLaunchKernelGGL(transpose_cast_kernel, dim3((DMODEL / 32) * (NQKV / 32)), dim3(256), 0,
                     stream, w_qkv, wqkvT, DMODEL, NQKV);
  hipLaunchKernelGGL(transpose_cast_kernel, dim3((DINNER / 32) * (DMODEL / 32)), dim3(256), 0,
                     stream, w_out, woutT, DINNER, DMODEL);
  hipLaunchKernelGGL(rmsnorm_kernel, dim3(BATCH * SEQ), dim3(256), 0, stream, x, gamma, normed);
  hipLaunchKernelGGL(qkv_gemm_kernel, dim3((BATCH * SEQ / BM) * (NQKV / BN)), dim3(256), 0,
                     stream, normed, wqkvT, qbuf, kbuf, vtbuf);
  hipLaunchKernelGGL(attn_kernel, dim3(BATCH * NHEAD * 16), dim3(256), 0, stream,
                     qbuf, kbuf, vtbuf, aout);
  hipLaunchKernelGGL(out_gemm_kernel, dim3((BATCH * SEQ / BM) * (DMODEL / BN)), dim3(256), 0,
                     stream, aout, woutT, out);
}